// Round 3
// baseline (195.186 us; speedup 1.0000x reference)
//
#include <hip/hip_runtime.h>
#include <cstddef>

#define HH 224
#define WW 608
#define HWSZ (HH * WW)

__device__ __forceinline__ float lrelu(float v) { return v > 0.0f ? v : 0.01f * v; }

// CondMul with the output dim split across an 8-lane group (sub-lane s = tid&7).
// Weight layout [i=0..31][o=0..CO-1] (wmat already offset by the gather index).
// Activations distributed 4 per lane: lane s' holds act[ii] = x[4*s'+ii].
// Lane s computes acc[j] = y[s*CH+j], accumulating i ascending (matches ref order).
template <int CO>
__device__ __forceinline__ void cm8(const float* __restrict__ wmat,
                                    const float* __restrict__ bvec,
                                    int s, const float (&act)[4], float (&acc)[CO / 8]) {
    constexpr int CH = CO / 8;
#pragma unroll
    for (int j = 0; j < CH; j++) acc[j] = 0.0f;
#pragma unroll
    for (int sp = 0; sp < 8; sp++) {
#pragma unroll
        for (int ii = 0; ii < 4; ii++) {
            float xi = __shfl(act[ii], sp, 8);      // x[4*sp+ii] broadcast in group
            const float* wr = wmat + (sp * 4 + ii) * CO + s * CH;
            if constexpr (CH == 4) {
                float4 a = *reinterpret_cast<const float4*>(wr);
                acc[0] = fmaf(xi, a.x, acc[0]); acc[1] = fmaf(xi, a.y, acc[1]);
                acc[2] = fmaf(xi, a.z, acc[2]); acc[3] = fmaf(xi, a.w, acc[3]);
            } else {
                float2 a = *reinterpret_cast<const float2*>(wr);
                acc[0] = fmaf(xi, a.x, acc[0]); acc[1] = fmaf(xi, a.y, acc[1]);
            }
        }
    }
#pragma unroll
    for (int j = 0; j < CH; j++) acc[j] += bvec[s * CH + j];
}

__device__ __forceinline__ void wb_lrelu4(float (&act)[4], const float (&acc)[4]) {
#pragma unroll
    for (int j = 0; j < 4; j++) act[j] = lrelu(acc[j]);
}

// First-max argmax over 16 values distributed 2-per-lane across the 8-lane group.
__device__ __forceinline__ int argmax8(const float (&v)[2], int s) {
    float bv = v[0];
    int bi = 2 * s;
    if (v[1] > bv) { bv = v[1]; bi = 2 * s + 1; }
#pragma unroll
    for (int m = 1; m <= 4; m <<= 1) {
        float ov = __shfl_xor(bv, m, 8);
        int oi = __shfl_xor(bi, m, 8);
        if (ov > bv || (ov == bv && oi < bi)) { bv = ov; bi = oi; }
    }
    return bi;   // all 8 lanes converge to (max value, lowest index)
}

extern "C" __global__ __launch_bounds__(256, 8)
void regressor_fused(const float* __restrict__ x_in,
                     const float* __restrict__ w1_0, const float* __restrict__ b1_0,
                     const float* __restrict__ w1_1, const float* __restrict__ b1_1,
                     const float* __restrict__ w1_2, const float* __restrict__ b1_2,
                     const float* __restrict__ w2_0, const float* __restrict__ b2_0,
                     const float* __restrict__ w2_1, const float* __restrict__ b2_1,
                     const float* __restrict__ w2_2, const float* __restrict__ b2_2,
                     const float* __restrict__ w3_0, const float* __restrict__ b3_0,
                     const float* __restrict__ w3_1, const float* __restrict__ b3_1,
                     const float* __restrict__ w3_2, const float* __restrict__ b3_2,
                     const float* __restrict__ wr0, const float* __restrict__ br0,
                     const float* __restrict__ wr1, const float* __restrict__ br1,
                     float* __restrict__ out) {
    const int h = blockIdx.y;
    const int tid = threadIdx.x;
    const int p = tid >> 3;          // pixel within block (0..31)
    const int s = tid & 7;           // output-chunk sub-lane (0..7)
    const int w = blockIdx.x * 32 + p;   // 608 = 19*32 exactly, no tail
    const int base = h * WW + w;

    // ---- stage-1 per-line weights, staged transposed to [i][o] in LDS ----
    __shared__ __align__(16) float sW0[1024];
    __shared__ __align__(16) float sW1[1024];
    __shared__ __align__(16) float sW2[512];
    for (int t = tid; t < 1024; t += 256) {
        int i = t >> 5, o = t & 31;
        sW0[t] = w1_0[h * 1024 + o * 32 + i];
        sW1[t] = w1_1[h * 1024 + o * 32 + i];
    }
    for (int t = tid; t < 512; t += 256) {
        int i = t >> 4, o = t & 15;
        sW2[t] = w1_2[h * 512 + o * 32 + i];
    }
    __syncthreads();

    float act[4], acc4[4], acc2[2];

    // ---------------- stage 1: per-line MLP -> class1 ----------------
#pragma unroll
    for (int ii = 0; ii < 4; ii++)
        act[ii] = __builtin_nontemporal_load(&x_in[(4 * s + ii) * HWSZ + base]);
    cm8<32>(sW0, b1_0 + h * 32, s, act, acc4);
    wb_lrelu4(act, acc4);
    cm8<32>(sW1, b1_1 + h * 32, s, act, acc4);
    wb_lrelu4(act, acc4);
    cm8<16>(sW2, b1_2 + h * 16, s, act, acc2);
    const int i1 = argmax8(acc2, s);

    // ---------------- stage 2: CondMul on (line, class1) ----------------
#pragma unroll
    for (int ii = 0; ii < 4; ii++)
        act[ii] = __builtin_nontemporal_load(&x_in[(32 + 4 * s + ii) * HWSZ + base]);
    const size_t idx2 = (size_t)h * 16 + (size_t)i1;
    cm8<32>(w2_0 + idx2 * 1024, b2_0 + idx2 * 32, s, act, acc4);
    wb_lrelu4(act, acc4);
    cm8<32>(w2_1 + idx2 * 1024, b2_1 + idx2 * 32, s, act, acc4);
    wb_lrelu4(act, acc4);
    cm8<16>(w2_2 + idx2 * 512, b2_2 + idx2 * 16, s, act, acc2);
    const int i2 = argmax8(acc2, s);

    const int inds12 = i1 * 12 + (i2 - 2);               // unclipped (used below)
    const int c12 = min(max(inds12, 0), 191);
    const size_t idx3 = (size_t)h * 192 + (size_t)c12;

    // ---------------- stage 3: CondMul on (line, class12) ----------------
#pragma unroll
    for (int ii = 0; ii < 4; ii++)
        act[ii] = __builtin_nontemporal_load(&x_in[(64 + 4 * s + ii) * HWSZ + base]);
    cm8<32>(w3_0 + idx3 * 1024, b3_0 + idx3 * 32, s, act, acc4);
    wb_lrelu4(act, acc4);
    cm8<32>(w3_1 + idx3 * 1024, b3_1 + idx3 * 32, s, act, acc4);
    wb_lrelu4(act, acc4);
    cm8<16>(w3_2 + idx3 * 512, b3_2 + idx3 * 16, s, act, acc2);
    const int i3 = argmax8(acc2, s);

    const int inds123 = min(max(inds12 * 10 + (i3 - 3), 0), 1919);

    // ---------------- regressor at predicted leaf ----------------
#pragma unroll
    for (int ii = 0; ii < 4; ii++)
        act[ii] = __builtin_nontemporal_load(&x_in[(96 + 4 * s + ii) * HWSZ + base]);
    const size_t idxs = (size_t)h * 384 + (size_t)(inds123 / 5);
    cm8<32>(wr0 + idxs * 1024, br0 + idxs * 32, s, act, acc4);
    wb_lrelu4(act, acc4);

    const size_t idxr = (size_t)h * 1920 + (size_t)inds123;
    const float* __restrict__ wr1r = wr1 + idxr * 32 + 4 * s;
    float4 wa = *reinterpret_cast<const float4*>(wr1r);
    float rpart = 0.0f;
    rpart = fmaf(act[0], wa.x, rpart); rpart = fmaf(act[1], wa.y, rpart);
    rpart = fmaf(act[2], wa.z, rpart); rpart = fmaf(act[3], wa.w, rpart);
    rpart += __shfl_xor(rpart, 1, 8);
    rpart += __shfl_xor(rpart, 2, 8);
    rpart += __shfl_xor(rpart, 4, 8);
    const float r = rpart + br1[idxr];

    if (s == 0) {
        float v = ((float)inds123 + r) * (1.0f / 1920.0f);
        __builtin_nontemporal_store((v - 0.1f) * 1.25f, &out[base]);
    }
}

extern "C" void kernel_launch(void* const* d_in, const int* in_sizes, int n_in,
                              void* d_out, int out_size, void* d_ws, size_t ws_size,
                              hipStream_t stream) {
    const float* p[23];
    for (int i = 0; i < 23; i++) p[i] = (const float*)d_in[i];
    dim3 grid(19, HH);   // 32 pixels per block, 8 lanes per pixel
    regressor_fused<<<grid, 256, 0, stream>>>(
        p[0],
        p[1], p[2], p[3], p[4], p[5], p[6],
        p[7], p[8], p[9], p[10], p[11], p[12],
        p[13], p[14], p[15], p[16], p[17], p[18],
        p[19], p[20], p[21], p[22],
        (float*)d_out);
}

// Round 4
// 137.693 us; speedup vs baseline: 1.4175x; 1.4175x over previous
//
#include <hip/hip_runtime.h>
#include <cstddef>

#define HH 224
#define WW 608
#define HWSZ (HH * WW)

__device__ __forceinline__ float lrelu(float v) { return v > 0.0f ? v : 0.01f * v; }

// CondMul with the output dim split across a 4-lane group (lane sub-index s).
// Weight layout [idx][i=0..31][o=0..CO-1] (wmat already offset by idx).
// Activations x[i] live distributed: lane s' of the group holds act[ii] = x[8*s'+ii].
// Each lane computes acc[j] = y[s*CH + j], accumulating i ascending (matches ref).
template <int CO>
__device__ __forceinline__ void cm4(const float* __restrict__ wmat,
                                    const float* __restrict__ bvec,
                                    int s, const float (&act)[8], float (&acc)[CO / 4]) {
    constexpr int CH = CO / 4;
#pragma unroll
    for (int j = 0; j < CH; j++) acc[j] = 0.0f;
#pragma unroll
    for (int sp = 0; sp < 4; sp++) {
#pragma unroll
        for (int ii = 0; ii < 8; ii++) {
            float xi = __shfl(act[ii], sp, 4);          // x[8*sp+ii], broadcast in group
            const float* wr = wmat + (sp * 8 + ii) * CO + s * CH;
            if constexpr (CH == 8) {
                float4 a = *reinterpret_cast<const float4*>(wr);
                float4 b = *reinterpret_cast<const float4*>(wr + 4);
                acc[0] = fmaf(xi, a.x, acc[0]); acc[1] = fmaf(xi, a.y, acc[1]);
                acc[2] = fmaf(xi, a.z, acc[2]); acc[3] = fmaf(xi, a.w, acc[3]);
                acc[4] = fmaf(xi, b.x, acc[4]); acc[5] = fmaf(xi, b.y, acc[5]);
                acc[6] = fmaf(xi, b.z, acc[6]); acc[7] = fmaf(xi, b.w, acc[7]);
            } else {
                float4 a = *reinterpret_cast<const float4*>(wr);
                acc[0] = fmaf(xi, a.x, acc[0]); acc[1] = fmaf(xi, a.y, acc[1]);
                acc[2] = fmaf(xi, a.z, acc[2]); acc[3] = fmaf(xi, a.w, acc[3]);
            }
        }
    }
#pragma unroll
    for (int j = 0; j < CH; j++) acc[j] += bvec[s * CH + j];
}

__device__ __forceinline__ void wb_lrelu8(float (&act)[8], const float (&acc)[8]) {
#pragma unroll
    for (int j = 0; j < 8; j++) act[j] = lrelu(acc[j]);
}

// First-max argmax over 16 values distributed 4-per-lane across the 4-lane group.
__device__ __forceinline__ int argmax4(const float (&v)[4], int s) {
    float bv = v[0];
    int bi = 4 * s;
#pragma unroll
    for (int j = 1; j < 4; j++) {
        if (v[j] > bv) { bv = v[j]; bi = 4 * s + j; }
    }
#pragma unroll
    for (int m = 1; m <= 2; m <<= 1) {
        float ov = __shfl_xor(bv, m, 4);
        int oi = __shfl_xor(bi, m, 4);
        if (ov > bv || (ov == bv && oi < bi)) { bv = ov; bi = oi; }
    }
    return bi;   // all 4 lanes converge to (max value, lowest index)
}

extern "C" __global__ __launch_bounds__(256, 4)
void regressor_fused(const float* __restrict__ x_in,
                     const float* __restrict__ w1_0, const float* __restrict__ b1_0,
                     const float* __restrict__ w1_1, const float* __restrict__ b1_1,
                     const float* __restrict__ w1_2, const float* __restrict__ b1_2,
                     const float* __restrict__ w2_0, const float* __restrict__ b2_0,
                     const float* __restrict__ w2_1, const float* __restrict__ b2_1,
                     const float* __restrict__ w2_2, const float* __restrict__ b2_2,
                     const float* __restrict__ w3_0, const float* __restrict__ b3_0,
                     const float* __restrict__ w3_1, const float* __restrict__ b3_1,
                     const float* __restrict__ w3_2, const float* __restrict__ b3_2,
                     const float* __restrict__ wr0, const float* __restrict__ br0,
                     const float* __restrict__ wr1, const float* __restrict__ br1,
                     float* __restrict__ out) {
    // XCD line-grouping swizzle: bid = r + 8*(x + 10*g), h = 8*g + r.
    // All 10 blocks of a line share bid%8 -> same XCD -> one L2 copy of the
    // line's stage-2/3/regressor tables instead of 8 replicas.
    const int bid = blockIdx.x;
    const int r = bid & 7;
    const int t = bid >> 3;
    const int xblk = t % 10;
    const int g = t / 10;
    const int h = 8 * g + r;

    const int tid = threadIdx.x;
    const int p = tid >> 2;          // pixel within block (0..63)
    const int s = tid & 3;           // output-chunk sub-lane (0..3)
    const int w = xblk * 64 + p;
    const bool valid = (w < WW);
    const int wc = valid ? w : (WW - 1);   // tail lanes compute a duplicate pixel
    const int base = h * WW + wc;

    // ---- stage-1 per-line weights, staged transposed to [i][o] in LDS ----
    __shared__ __align__(16) float sW0[1024];
    __shared__ __align__(16) float sW1[1024];
    __shared__ __align__(16) float sW2[512];
    for (int tt = tid; tt < 1024; tt += 256) {
        int i = tt >> 5, o = tt & 31;
        sW0[tt] = w1_0[h * 1024 + o * 32 + i];
        sW1[tt] = w1_1[h * 1024 + o * 32 + i];
    }
    for (int tt = tid; tt < 512; tt += 256) {
        int i = tt >> 4, o = tt & 15;
        sW2[tt] = w1_2[h * 512 + o * 32 + i];
    }
    __syncthreads();

    float act1[8], act2[8], act3[8], actr[8], acc8[8], acc4[4];

    // Hoist ALL stages' x loads: class-independent, so issue them before any
    // gather and let the streaming HBM traffic overlap the condmul chains.
#pragma unroll
    for (int ii = 0; ii < 8; ii++) {
        act1[ii] = x_in[(8 * s + ii) * HWSZ + base];
        act2[ii] = x_in[(32 + 8 * s + ii) * HWSZ + base];
        act3[ii] = x_in[(64 + 8 * s + ii) * HWSZ + base];
        actr[ii] = x_in[(96 + 8 * s + ii) * HWSZ + base];
    }

    // ---------------- stage 1: per-line MLP -> class1 ----------------
    cm4<32>(sW0, b1_0 + h * 32, s, act1, acc8);
    wb_lrelu8(act1, acc8);
    cm4<32>(sW1, b1_1 + h * 32, s, act1, acc8);
    wb_lrelu8(act1, acc8);
    cm4<16>(sW2, b1_2 + h * 16, s, act1, acc4);
    const int i1 = argmax4(acc4, s);

    // ---------------- stage 2: CondMul on (line, class1) ----------------
    const size_t idx2 = (size_t)h * 16 + (size_t)i1;
    cm4<32>(w2_0 + idx2 * 1024, b2_0 + idx2 * 32, s, act2, acc8);
    wb_lrelu8(act2, acc8);
    cm4<32>(w2_1 + idx2 * 1024, b2_1 + idx2 * 32, s, act2, acc8);
    wb_lrelu8(act2, acc8);
    cm4<16>(w2_2 + idx2 * 512, b2_2 + idx2 * 16, s, act2, acc4);
    const int i2 = argmax4(acc4, s);

    const int inds12 = i1 * 12 + (i2 - 2);               // unclipped (used below)
    const int c12 = min(max(inds12, 0), 191);
    const size_t idx3 = (size_t)h * 192 + (size_t)c12;

    // ---------------- stage 3: CondMul on (line, class12) ----------------
    cm4<32>(w3_0 + idx3 * 1024, b3_0 + idx3 * 32, s, act3, acc8);
    wb_lrelu8(act3, acc8);
    cm4<32>(w3_1 + idx3 * 1024, b3_1 + idx3 * 32, s, act3, acc8);
    wb_lrelu8(act3, acc8);
    cm4<16>(w3_2 + idx3 * 512, b3_2 + idx3 * 16, s, act3, acc4);
    const int i3 = argmax4(acc4, s);

    const int inds123 = min(max(inds12 * 10 + (i3 - 3), 0), 1919);

    // ---------------- regressor at predicted leaf ----------------
    const size_t idxs = (size_t)h * 384 + (size_t)(inds123 / 5);
    cm4<32>(wr0 + idxs * 1024, br0 + idxs * 32, s, actr, acc8);
    wb_lrelu8(actr, acc8);

    const size_t idxr = (size_t)h * 1920 + (size_t)inds123;
    const float* __restrict__ wr1r = wr1 + idxr * 32 + 8 * s;
    float4 wa = *reinterpret_cast<const float4*>(wr1r);
    float4 wb = *reinterpret_cast<const float4*>(wr1r + 4);
    float rpart = 0.0f;
    rpart = fmaf(actr[0], wa.x, rpart); rpart = fmaf(actr[1], wa.y, rpart);
    rpart = fmaf(actr[2], wa.z, rpart); rpart = fmaf(actr[3], wa.w, rpart);
    rpart = fmaf(actr[4], wb.x, rpart); rpart = fmaf(actr[5], wb.y, rpart);
    rpart = fmaf(actr[6], wb.z, rpart); rpart = fmaf(actr[7], wb.w, rpart);
    rpart += __shfl_xor(rpart, 1, 4);
    rpart += __shfl_xor(rpart, 2, 4);
    const float rr = rpart + br1[idxr];

    if (s == 0 && valid) {
        float v = ((float)inds123 + rr) * (1.0f / 1920.0f);
        out[h * WW + w] = (v - 0.1f) * 1.25f;
    }
}

extern "C" void kernel_launch(void* const* d_in, const int* in_sizes, int n_in,
                              void* d_out, int out_size, void* d_ws, size_t ws_size,
                              hipStream_t stream) {
    const float* p[23];
    for (int i = 0; i < 23; i++) p[i] = (const float*)d_in[i];
    regressor_fused<<<dim3(2240), 256, 0, stream>>>(
        p[0],
        p[1], p[2], p[3], p[4], p[5], p[6],
        p[7], p[8], p[9], p[10], p[11], p[12],
        p[13], p[14], p[15], p[16], p[17], p[18],
        p[19], p[20], p[21], p[22],
        (float*)d_out);
}